// Round 1
// baseline (82.223 us; speedup 1.0000x reference)
//
#include <hip/hip_runtime.h>

// Problem constants (from reference setup_inputs): B=8, C=256, H=64, W=48
#define BB 8
#define CC 256
#define NN 3072   // H*W
#define NCLS 8    // labels in [0,8)

// --- Kernel 1: per-batch class counts -------------------------------------
__global__ __launch_bounds__(256) void count_kernel(const int* __restrict__ label,
                                                    int* __restrict__ counts) {
    const int b = blockIdx.x;
    const int t = threadIdx.x;
    const int4* lab4 = reinterpret_cast<const int4*>(label + b * NN);

    int cnt[NCLS];
#pragma unroll
    for (int k = 0; k < NCLS; ++k) cnt[k] = 0;

#pragma unroll
    for (int i = 0; i < 3; ++i) {           // 3 * 256 * 4 = 3072
        int4 l = lab4[i * 256 + t];
        int ls0 = l.x, ls1 = l.y, ls2 = l.z, ls3 = l.w;
#pragma unroll
        for (int k = 0; k < NCLS; ++k) {
            cnt[k] += (ls0 == k) + (ls1 == k) + (ls2 == k) + (ls3 == k);
        }
    }

    // wave (64-lane) shuffle reduce
#pragma unroll
    for (int k = 0; k < NCLS; ++k) {
#pragma unroll
        for (int off = 32; off > 0; off >>= 1)
            cnt[k] += __shfl_down(cnt[k], off, 64);
    }

    __shared__ int wsum[4][NCLS];
    const int wave = t >> 6, lane = t & 63;
    if (lane == 0) {
#pragma unroll
        for (int k = 0; k < NCLS; ++k) wsum[wave][k] = cnt[k];
    }
    __syncthreads();
    if (t < NCLS)
        counts[b * NCLS + t] = wsum[0][t] + wsum[1][t] + wsum[2][t] + wsum[3][t];
}

// --- Kernel 2: fused class-sum + scatter ----------------------------------
// One block per (b,c) row of 3072 elements. 256 threads * 12 elems (float4).
__global__ __launch_bounds__(256) void ctx_kernel(const float* __restrict__ x,
                                                  const int* __restrict__ label,
                                                  const int* __restrict__ counts,
                                                  float* __restrict__ out) {
    const int bc = blockIdx.x;         // b * CC + c
    const int b  = bc >> 8;            // CC == 256
    const int t  = threadIdx.x;

    const float4* x4   = reinterpret_cast<const float4*>(x + (size_t)bc * NN);
    const int4*   lab4 = reinterpret_cast<const int4*>(label + b * NN);
    float4*       o4   = reinterpret_cast<float4*>(out + (size_t)bc * NN);

    int   labs[12];
    float vals[12];
#pragma unroll
    for (int i = 0; i < 3; ++i) {
        int4   l = lab4[i * 256 + t];
        float4 v = x4[i * 256 + t];
        labs[i * 4 + 0] = l.x; labs[i * 4 + 1] = l.y;
        labs[i * 4 + 2] = l.z; labs[i * 4 + 3] = l.w;
        vals[i * 4 + 0] = v.x; vals[i * 4 + 1] = v.y;
        vals[i * 4 + 2] = v.z; vals[i * 4 + 3] = v.w;
    }

    // predicated per-class accumulation (compile-time indices only)
    float acc[NCLS];
#pragma unroll
    for (int k = 0; k < NCLS; ++k) acc[k] = 0.f;
#pragma unroll
    for (int j = 0; j < 12; ++j) {
#pragma unroll
        for (int k = 0; k < NCLS; ++k)
            acc[k] += (labs[j] == k) ? vals[j] : 0.f;
    }

    // wave shuffle reduce
#pragma unroll
    for (int k = 0; k < NCLS; ++k) {
#pragma unroll
        for (int off = 32; off > 0; off >>= 1)
            acc[k] += __shfl_down(acc[k], off, 64);
    }

    __shared__ float wsum[4][NCLS];
    __shared__ float ssum[NCLS];
    __shared__ float sval[NCLS];
    const int wave = t >> 6, lane = t & 63;
    if (lane == 0) {
#pragma unroll
        for (int k = 0; k < NCLS; ++k) wsum[wave][k] = acc[k];
    }
    __syncthreads();
    if (t < NCLS)
        ssum[t] = wsum[0][t] + wsum[1][t] + wsum[2][t] + wsum[3][t];
    __syncthreads();
    if (t < NCLS) {
        float v;
        if (t == 0) {
            // label==0 rows average over ALL pixels (pair==1 everywhere)
            float tot = 0.f;
#pragma unroll
            for (int k = 0; k < NCLS; ++k) tot += ssum[k];
            v = tot * (1.0f / (float)NN);
        } else {
            float c = (float)counts[b * NCLS + t];
            v = ssum[t] / fmaxf(c, 1e-12f);   // denom = max(count, EPS)
        }
        sval[t] = v;
    }
    __syncthreads();

    // scatter: out[n] = sval[lab[n]]  (LDS broadcast reads, 8 distinct banks)
#pragma unroll
    for (int i = 0; i < 3; ++i) {
        float4 o;
        o.x = sval[labs[i * 4 + 0]];
        o.y = sval[labs[i * 4 + 1]];
        o.z = sval[labs[i * 4 + 2]];
        o.w = sval[labs[i * 4 + 3]];
        o4[i * 256 + t] = o;
    }
}

extern "C" void kernel_launch(void* const* d_in, const int* in_sizes, int n_in,
                              void* d_out, int out_size, void* d_ws, size_t ws_size,
                              hipStream_t stream) {
    const float* x     = (const float*)d_in[0];
    const int*   label = (const int*)d_in[1];
    float*       out   = (float*)d_out;
    int*         counts = (int*)d_ws;   // 8*8 ints

    count_kernel<<<BB, 256, 0, stream>>>(label, counts);
    ctx_kernel<<<BB * CC, 256, 0, stream>>>(x, label, counts, out);
}

// Round 2
// 81.174 us; speedup vs baseline: 1.0129x; 1.0129x over previous
//
#include <hip/hip_runtime.h>

// Problem constants (from reference setup_inputs): B=8, C=256, H=64, W=48
#define BB 8
#define CC 256
#define NN 3072   // H*W
#define NCLS 8    // labels in [0,8)

// Fully fused kernel: one block per (b,c) row of 3072 elements.
// Each block computes per-class sums AND per-class counts from the labels it
// already loads, then scatters out[n] = classmean[lab[n]].
__global__ __launch_bounds__(256) void ctx_kernel(const float* __restrict__ x,
                                                  const int* __restrict__ label,
                                                  float* __restrict__ out) {
    const int bc = blockIdx.x;         // b * CC + c
    const int b  = bc >> 8;            // CC == 256
    const int t  = threadIdx.x;

    const float4* x4   = reinterpret_cast<const float4*>(x + (size_t)bc * NN);
    const int4*   lab4 = reinterpret_cast<const int4*>(label + b * NN);
    float4*       o4   = reinterpret_cast<float4*>(out + (size_t)bc * NN);

    int   labs[12];
    float vals[12];
#pragma unroll
    for (int i = 0; i < 3; ++i) {
        int4   l = lab4[i * 256 + t];
        float4 v = x4[i * 256 + t];
        labs[i * 4 + 0] = l.x; labs[i * 4 + 1] = l.y;
        labs[i * 4 + 2] = l.z; labs[i * 4 + 3] = l.w;
        vals[i * 4 + 0] = v.x; vals[i * 4 + 1] = v.y;
        vals[i * 4 + 2] = v.z; vals[i * 4 + 3] = v.w;
    }

    // Predicated per-class value accumulation (VALU) + per-class counts via
    // ballot/popcount (SALU pipe, wave-uniform result -> no shuffle reduce).
    float acc[NCLS];
    int   cntw[NCLS];                  // wave-wide count, uniform across lanes
#pragma unroll
    for (int k = 0; k < NCLS; ++k) { acc[k] = 0.f; cntw[k] = 0; }
#pragma unroll
    for (int j = 0; j < 12; ++j) {
#pragma unroll
        for (int k = 0; k < NCLS; ++k) {
            bool m = (labs[j] == k);
            acc[k] += m ? vals[j] : 0.f;
            cntw[k] += (int)__popcll(__ballot(m));
        }
    }

    // wave (64-lane) butterfly reduce for the value sums
#pragma unroll
    for (int k = 0; k < NCLS; ++k) {
#pragma unroll
        for (int off = 32; off > 0; off >>= 1)
            acc[k] += __shfl_xor(acc[k], off, 64);
    }

    __shared__ float wsum[4][NCLS];
    __shared__ int   wcnt[4][NCLS];
    __shared__ float sval[NCLS];
    const int wave = t >> 6, lane = t & 63;
    if (lane == 0) {
#pragma unroll
        for (int k = 0; k < NCLS; ++k) {
            wsum[wave][k] = acc[k];
            wcnt[wave][k] = cntw[k];
        }
    }
    __syncthreads();
    if (t < NCLS) {
        float s = wsum[0][t] + wsum[1][t] + wsum[2][t] + wsum[3][t];
        // class-k mean; class 0 handled below (needs total over ALL classes)
        int   c = wcnt[0][t] + wcnt[1][t] + wcnt[2][t] + wcnt[3][t];
        wsum[0][t] = s;                 // reuse LDS to stash totals
        wcnt[0][t] = c;
    }
    __syncthreads();
    if (t < NCLS) {
        float v;
        if (t == 0) {
            // label==0 rows average over ALL pixels (pair==1 everywhere)
            float tot = 0.f;
#pragma unroll
            for (int k = 0; k < NCLS; ++k) tot += wsum[0][k];
            v = tot * (1.0f / (float)NN);
        } else {
            float c = (float)wcnt[0][t];
            v = wsum[0][t] / fmaxf(c, 1e-12f);   // denom = max(count, EPS)
        }
        sval[t] = v;
    }
    __syncthreads();

    // scatter: out[n] = sval[lab[n]]  (LDS broadcast reads)
#pragma unroll
    for (int i = 0; i < 3; ++i) {
        float4 o;
        o.x = sval[labs[i * 4 + 0]];
        o.y = sval[labs[i * 4 + 1]];
        o.z = sval[labs[i * 4 + 2]];
        o.w = sval[labs[i * 4 + 3]];
        o4[i * 256 + t] = o;
    }
}

extern "C" void kernel_launch(void* const* d_in, const int* in_sizes, int n_in,
                              void* d_out, int out_size, void* d_ws, size_t ws_size,
                              hipStream_t stream) {
    const float* x     = (const float*)d_in[0];
    const int*   label = (const int*)d_in[1];
    float*       out   = (float*)d_out;

    ctx_kernel<<<BB * CC, 256, 0, stream>>>(x, label, out);
}